// Round 1
// baseline (442.042 us; speedup 1.0000x reference)
//
#include <hip/hip_runtime.h>
#include <stdint.h>

#define IMG_H 256
#define IMG_W 256
#define ROWS_PER_WAVE 32          // output rows per wave
#define STRIPS 8                  // IMG_H / ROWS_PER_WAVE
#define N_IMG 1024                // 16 batch * 64 channels
#define WAVES_PER_BLOCK 4

__device__ __forceinline__ float4 fmax4(const float4 a, const float4 b) {
    return make_float4(fmaxf(a.x, b.x), fmaxf(a.y, b.y), fmaxf(a.z, b.z), fmaxf(a.w, b.w));
}

// Fused hex maxpool, register-streaming version: no LDS, no barriers.
// One wave spans the full 256-col row (64 lanes x float4). Rolling 5-row
// register window; per output row: 1 coalesced load (row h+3 prefetch),
// ~50 VALU, 1 coalesced store. OOB rows/cols -> 0.0 (matches jnp.pad).
// w even: col w rows h-2..h+2 ; cols w+-1 rows h-2..h+1 ; cols w+-2 rows h-1..h+1
// w odd : col w rows h-2..h+2 ; cols w+-1 rows h-1..h+2 ; cols w+-2 rows h-1..h+1
__global__ __launch_bounds__(256, 8) void hex_maxpool_stream(const float* __restrict__ in,
                                                             float* __restrict__ out) {
    const int lane  = threadIdx.x & 63;
    const int wave  = threadIdx.x >> 6;
    const int W     = blockIdx.x * WAVES_PER_BLOCK + wave;   // global wave id
    const int img   = W >> 3;                                // 8 strips per image
    const int strip = W & 7;
    const int S     = strip * ROWS_PER_WAVE;                 // first output row

    const float* p = in  + (size_t)img * (IMG_H * IMG_W) + lane * 4;
    float*       q = out + (size_t)img * (IMG_H * IMG_W) + lane * 4;

    auto loadrow = [&](int g) -> float4 {
        if ((unsigned)g < (unsigned)IMG_H)                   // wave-uniform branch
            return *reinterpret_cast<const float4*>(p + (size_t)g * IMG_W);
        return make_float4(0.f, 0.f, 0.f, 0.f);
    };

    // Verified-correct hex window reduction (identical math to the 425.6 us kernel).
    auto hexrow = [&](const float4 w0, const float4 w1, const float4 w2,
                      const float4 w3, const float4 w4) -> float4 {
        const float4 m3 = fmax4(fmax4(w1, w2), w3); // rows h-1..h+1
        const float4 bu = fmax4(m3, w0);            // rows h-2..h+1
        const float4 bd = fmax4(m3, w4);            // rows h-1..h+2
        const float4 a5 = fmax4(bu, w4);            // rows h-2..h+2

        float Lbuw = __shfl_up(bu.w, 1);
        float Lm3z = __shfl_up(m3.z, 1);
        float Lm3w = __shfl_up(m3.w, 1);
        float Rbdx = __shfl_down(bd.x, 1);
        float Rm3x = __shfl_down(m3.x, 1);
        float Rm3y = __shfl_down(m3.y, 1);
        if (lane == 0)  { Lbuw = 0.f; Lm3z = 0.f; Lm3w = 0.f; }  // cols -1,-2 pad(0)
        if (lane == 63) { Rbdx = 0.f; Rm3x = 0.f; Rm3y = 0.f; }  // cols 256,257 pad(0)

        float4 o;
        o.x = fmaxf(fmaxf(fmaxf(a5.x, Lbuw), bu.y), fmaxf(Lm3z, m3.z)); // even col
        o.y = fmaxf(fmaxf(fmaxf(a5.y, bd.x), bd.z), fmaxf(Lm3w, m3.w)); // odd col
        o.z = fmaxf(fmaxf(fmaxf(a5.z, bu.y), bu.w), fmaxf(m3.x, Rm3x)); // even col
        o.w = fmaxf(fmaxf(fmaxf(a5.w, bd.z), Rbdx), fmaxf(m3.y, Rm3y)); // odd col
        return o;
    };

    // Prime the 5-row rolling window (rows S-2 .. S+2).
    float4 r0 = loadrow(S - 2);
    float4 r1 = loadrow(S - 1);
    float4 r2 = loadrow(S);
    float4 r3 = loadrow(S + 1);
    float4 r4 = loadrow(S + 2);

#pragma unroll 2
    for (int k = 0; k < ROWS_PER_WAVE; ++k) {
        const float4 nx = loadrow(S + 3 + k);    // prefetch before compute
        const float4 o  = hexrow(r0, r1, r2, r3, r4);
        *reinterpret_cast<float4*>(q + (size_t)(S + k) * IMG_W) = o;
        r0 = r1; r1 = r2; r2 = r3; r3 = r4; r4 = nx;
    }
}

extern "C" void kernel_launch(void* const* d_in, const int* in_sizes, int n_in,
                              void* d_out, int out_size, void* d_ws, size_t ws_size,
                              hipStream_t stream) {
    (void)in_sizes; (void)n_in; (void)d_ws; (void)ws_size; (void)out_size;
    const float* in = (const float*)d_in[0];
    float* out = (float*)d_out;
    // 1024 images * 8 strips / 4 waves per block = 2048 blocks of 256 threads
    hex_maxpool_stream<<<(N_IMG * STRIPS) / WAVES_PER_BLOCK, 256, 0, stream>>>(in, out);
}